// Round 7
// baseline (237.898 us; speedup 1.0000x reference)
//
#include <hip/hip_runtime.h>
#include <stdint.h>

#define G_ 8
#define S_ 16
#define H_ 512
#define TB 64
#define NTH 512

typedef _Float16 h16;
typedef _Float16 h16x8 __attribute__((ext_vector_type(8)));
typedef float f32x4 __attribute__((ext_vector_type(4)));
typedef float f32x16 __attribute__((ext_vector_type(16)));

#define XB_STRIDE 24                      // h16 units per xb row (48 B)
#define HB_BYTES (TB * 1024)              // 64 rows x 512 h16 = 64 KB
#define SMEM_BYTES (HB_BYTES + TB * XB_STRIDE * 2)   // ~67 KB -> 2 blocks/CU

__device__ __forceinline__ float swishf(float v, float sp) {
    const float e = __expf(-v * sp);
    return v * __builtin_amdgcn_rcpf(1.0f + e) * (1.0f / 1.1f);
}

// pack two f32 -> one u32 of 2x fp16 (RTZ)
__device__ __forceinline__ uint32_t pk16(float a, float b) {
    return __builtin_bit_cast(uint32_t, __builtin_amdgcn_cvt_pkrtz(a, b));
}

// swizzled byte offset into hbuf: row stride 1024B, XOR bits 4-6 with row&7
__device__ __forceinline__ uint32_t hswz(int row, uint32_t byte_in_row) {
    return (uint32_t)row * 1024u + (byte_in_row ^ (((uint32_t)(row & 7)) << 4));
}

// ---- A-operand (weight) fragment loaders ----
// 32x32x16 frag, ks-major packed layout [ks][nb=0..15][64][8]:
// the 4 frags a wave needs per ks sit at ONE base + offset:{0,1024,2048,3072}.
// lane ln: m-row = nb*32 + (ln&31), k = ks*16 + (ln>>5)*8 + j.
template<bool USEWS>
__device__ __forceinline__ h16x8 loadA32ks(const h16* __restrict__ wpk,
                                           const float* __restrict__ wf,
                                           int ks, int nb, int ln, int Ksrc) {
    if constexpr (USEWS) {
        return *(const h16x8*)(wpk + (((size_t)ks * 16 + nb) * 64 + ln) * 8);
    } else {
        const int row = nb * 32 + (ln & 31);
        const int k = ks * 16 + (ln >> 5) * 8;
        const float* p = wf + (size_t)row * Ksrc + k;
        h16x8 r;
        #pragma unroll
        for (int j = 0; j < 8; ++j) r[j] = (h16)p[j];
        return r;
    }
}

// 16x16x32 frag (W4): lane ln: m-row = ln&15, k = ks32*32 + (ln>>4)*8 + j
template<bool USEWS>
__device__ __forceinline__ h16x8 loadA16(const h16* __restrict__ wpk,
                                         const float* __restrict__ wf,
                                         int ks32, int ln, int Ksrc) {
    if constexpr (USEWS) {
        return *(const h16x8*)(wpk + ((size_t)ks32 * 64 + ln) * 8);
    } else {
        const int row = ln & 15;
        const int k = ks32 * 32 + (ln >> 4) * 8;
        const float* p = wf + (size_t)row * Ksrc + k;
        h16x8 r;
        #pragma unroll
        for (int j = 0; j < 8; ++j) r[j] = (h16)p[j];
        return r;
    }
}

// D (32x32): col = lane&31 = batch-row (within this wave's 32-row half);
// o-row = (reg&3) + 8*(reg>>2) + 4*(lane>>5). 4 consecutive o per reg-quad ->
// cvt_pkrtz x2 -> one ds_write_b64.
__device__ __forceinline__ void swish_store32(const f32x16 (&acc)[4], char* hb,
                                              const float* __restrict__ bias, float sp,
                                              int os, int bh, int ln) {
    const int l31 = ln & 31, lh = ln >> 5;
    const int b = bh * 32 + l31;
    #pragma unroll
    for (int nb = 0; nb < 4; ++nb) {
        #pragma unroll
        for (int rq = 0; rq < 4; ++rq) {
            const int col0 = os * 128 + nb * 32 + rq * 8 + lh * 4;
            const f32x4 bv = *(const f32x4*)(bias + col0);
            const float v0 = swishf(acc[nb][rq * 4 + 0] + bv[0], sp);
            const float v1 = swishf(acc[nb][rq * 4 + 1] + bv[1], sp);
            const float v2 = swishf(acc[nb][rq * 4 + 2] + bv[2], sp);
            const float v3 = swishf(acc[nb][rq * 4 + 3] + bv[3], sp);
            const uint64_t u = (uint64_t)pk16(v0, v1)
                             | ((uint64_t)pk16(v2, v3) << 32);
            *(uint64_t*)(hb + hswz(b, (uint32_t)(col0 * 2))) = u;
        }
    }
}

// One H->H layer: wave tile 128 o-cols x 32 b-rows, 32x32x16 MFMA, K=512.
// Per ks: 4 A-loads (one base + imm offsets, L1-shared with twin wave) +
// ONE ds_read_b128 + 4 MFMA -> 256 B LDS per MFMA (halved vs 64x64 tile).
template<bool USEWS>
__device__ __forceinline__ void layerH32(f32x16 (&acc)[4],
                                         const h16* __restrict__ wpk, const float* __restrict__ wf,
                                         const char* __restrict__ hb, int os, int bh, int ln) {
    const int l31 = ln & 31, lh = ln >> 5;
    const int brow = bh * 32 + l31;
    #pragma unroll
    for (int nb = 0; nb < 4; ++nb) acc[nb] = (f32x16)(0.f);

    #pragma unroll 4
    for (int ks = 0; ks < 32; ++ks) {
        h16x8 a0 = loadA32ks<USEWS>(wpk, wf, ks, os * 4 + 0, ln, H_);
        h16x8 a1 = loadA32ks<USEWS>(wpk, wf, ks, os * 4 + 1, ln, H_);
        h16x8 a2 = loadA32ks<USEWS>(wpk, wf, ks, os * 4 + 2, ln, H_);
        h16x8 a3 = loadA32ks<USEWS>(wpk, wf, ks, os * 4 + 3, ln, H_);
        const h16x8 b = *(const h16x8*)(hb + hswz(brow, (uint32_t)(ks * 32 + lh * 16)));
        __builtin_amdgcn_s_setprio(1);
        acc[0] = __builtin_amdgcn_mfma_f32_32x32x16_f16(a0, b, acc[0], 0, 0, 0);
        acc[1] = __builtin_amdgcn_mfma_f32_32x32x16_f16(a1, b, acc[1], 0, 0, 0);
        acc[2] = __builtin_amdgcn_mfma_f32_32x32x16_f16(a2, b, acc[2], 0, 0, 0);
        acc[3] = __builtin_amdgcn_mfma_f32_32x32x16_f16(a3, b, acc[3], 0, 0, 0);
        __builtin_amdgcn_s_setprio(0);
    }
}

template<bool USEWS>
__global__ __launch_bounds__(NTH, 4) void mlp_fused(
    const float* __restrict__ x,
    const float* __restrict__ W1f, const float* __restrict__ b1, const float* __restrict__ be1,
    const float* __restrict__ W2f, const float* __restrict__ b2, const float* __restrict__ be2,
    const float* __restrict__ W3f, const float* __restrict__ b3, const float* __restrict__ be3,
    const float* __restrict__ W4f, const float* __restrict__ b4,
    const h16* __restrict__ W1p, const h16* __restrict__ W2p,
    const h16* __restrict__ W3p, const h16* __restrict__ W4p,
    float* __restrict__ out) {
    extern __shared__ char smem[];
    h16* __restrict__ xb = (h16*)(smem + HB_BYTES);

    const int bid = blockIdx.x;
    const int g = bid & 7;                 // group == XCD; co-resident blocks share weights in L2
    const int rowbase = (bid >> 3) * TB;
    const int tid = threadIdx.x;
    const int wv = tid >> 6;
    const int ln = tid & 63;
    const int l31 = ln & 31;
    const int lh = ln >> 5;
    const int os = wv & 3;                 // o-slice: 128 cols
    const int bh = wv >> 2;                // b-half: 32 rows

    const float sp1 = log1pf(__expf(be1[g]));
    const float sp2 = log1pf(__expf(be2[g]));
    const float sp3 = log1pf(__expf(be3[g]));

    const h16* w1p = W1p + (size_t)g * H_ * S_;
    const h16* w2p = W2p + (size_t)g * H_ * H_;
    const h16* w3p = W3p + (size_t)g * H_ * H_;
    const h16* w4p = W4p + (size_t)g * S_ * H_;
    const float* w1f = W1f + (size_t)g * H_ * S_;
    const float* w2f = W2f + (size_t)g * H_ * H_;
    const float* w3f = W3f + (size_t)g * H_ * H_;
    const float* w4f = W4f + (size_t)g * S_ * H_;

    // stage x tile -> fp16 (K=16 exact for 32x32x16)
    {
        const int idx = tid * 2;                         // 64*16 = 1024 h16, 2 per thread
        const int r = idx >> 4, s = idx & 15;
        const float2 v = *(const float2*)(x + (size_t)(rowbase + r) * (G_ * S_) + g * S_ + s);
        *(uint32_t*)((char*)xb + (r * XB_STRIDE + s) * 2) = pk16(v.x, v.y);
    }
    __syncthreads();

    f32x16 acc[4];

    // ---- layer 1: A=W1[512,16] frags, B=x frags, single K-step ----
    {
        #pragma unroll
        for (int nb = 0; nb < 4; ++nb) acc[nb] = (f32x16)(0.f);
        h16x8 aW[4];
        #pragma unroll
        for (int nb = 0; nb < 4; ++nb)
            aW[nb] = loadA32ks<USEWS>(w1p, w1f, 0, os * 4 + nb, ln, S_);
        const h16x8 bX = *(const h16x8*)(xb + (bh * 32 + l31) * XB_STRIDE + lh * 8);
        #pragma unroll
        for (int nb = 0; nb < 4; ++nb)
            acc[nb] = __builtin_amdgcn_mfma_f32_32x32x16_f16(aW[nb], bX, acc[nb], 0, 0, 0);
    }
    swish_store32(acc, smem, b1 + g * H_, sp1, os, bh, ln);
    __syncthreads();

    // ---- layer 2 ----
    layerH32<USEWS>(acc, w2p, w2f, smem, os, bh, ln);
    __syncthreads();                       // all hbuf reads done
    swish_store32(acc, smem, b2 + g * H_, sp2, os, bh, ln);
    __syncthreads();

    // ---- layer 3 ----
    layerH32<USEWS>(acc, w3p, w3f, smem, os, bh, ln);
    __syncthreads();
    swish_store32(acc, smem, b3 + g * H_, sp3, os, bh, ln);
    __syncthreads();

    // ---- layer 4: A=W4[16,512] frags (16x16x32), B=act; D: col=b, rows=4 consec s ----
    if (wv < 4) {
        f32x4 a4 = {0.f, 0.f, 0.f, 0.f};
        const int l15 = ln & 15, lq = ln >> 4;
        #pragma unroll 4
        for (int ks = 0; ks < 16; ++ks) {
            const h16x8 a = loadA16<USEWS>(w4p, w4f, ks, ln, H_);
            const h16x8 b = *(const h16x8*)(smem + hswz(wv * 16 + l15,
                                                        (uint32_t)(ks * 64 + lq * 16)));
            a4 = __builtin_amdgcn_mfma_f32_16x16x32_f16(a, b, a4, 0, 0, 0);
        }
        const int brow = wv * 16 + l15;    // batch row
        const int s0 = lq * 4;             // 4 consecutive state channels
        const f32x4 bv = *(const f32x4*)(b4 + g * S_ + s0);
        f32x4 o4;
        #pragma unroll
        for (int r = 0; r < 4; ++r) o4[r] = a4[r] + bv[r];
        *(f32x4*)(out + (size_t)(rowbase + brow) * (G_ * S_) + g * S_ + s0) = o4;
    }
}

// ---- weight repack (32x32x16, ks-major): fp32 [G*N][Ks] -> per-group [ks][nb][64][8] ----
__global__ void packW32(const float* __restrict__ s, h16* __restrict__ d,
                        int KB, int Ks) {
    const int t = blockIdx.x * 256 + threadIdx.x;
    const int total = G_ * KB * 16 * 64;
    if (t >= total) return;
    const int ln = t & 63;
    const int blk = t >> 6;                // ((g*KB + ks)*16 + nb)
    const int nb = blk & 15;
    const int rest = blk >> 4;
    const int ks = rest % KB;
    const int g = rest / KB;
    const int row = g * H_ + nb * 32 + (ln & 31);
    const int k = ks * 16 + (ln >> 5) * 8;
    const float* p = s + (size_t)row * Ks + k;
    h16x8 o;
    #pragma unroll
    for (int j = 0; j < 8; ++j) o[j] = (h16)p[j];
    *(h16x8*)(d + (size_t)t * 8) = o;
}

// ---- weight repack (16x16x32, W4): fp32 [G*16][512] -> per-group [ks][64][8] ----
__global__ void packW16(const float* __restrict__ s, h16* __restrict__ d,
                        int NB_total, int KB, int Ks) {
    const int t = blockIdx.x * 256 + threadIdx.x;
    const int total = NB_total * KB * 64;
    if (t >= total) return;
    const int ln = t & 63;
    const int blk = t >> 6;
    const int kb = blk % KB;
    const int nbg = blk / KB;
    const int row = nbg * 16 + (ln & 15);
    const int k = kb * 32 + (ln >> 4) * 8;
    const float* p = s + (size_t)row * Ks + k;
    h16x8 o;
    #pragma unroll
    for (int j = 0; j < 8; ++j) o[j] = (h16)p[j];
    *(h16x8*)(d + (size_t)t * 8) = o;
}

extern "C" void kernel_launch(void* const* d_in, const int* in_sizes, int n_in,
                              void* d_out, int out_size, void* d_ws, size_t ws_size,
                              hipStream_t stream) {
    const float* x   = (const float*)d_in[0];
    const float* W1  = (const float*)d_in[1];
    const float* b1  = (const float*)d_in[2];
    const float* be1 = (const float*)d_in[3];
    const float* W2  = (const float*)d_in[4];
    const float* b2  = (const float*)d_in[5];
    const float* be2 = (const float*)d_in[6];
    const float* W3  = (const float*)d_in[7];
    const float* b3  = (const float*)d_in[8];
    const float* be3 = (const float*)d_in[9];
    const float* W4  = (const float*)d_in[10];
    const float* b4  = (const float*)d_in[11];
    float* out = (float*)d_out;

    const size_t nW2  = (size_t)G_ * H_ * H_;   // 2097152
    const size_t nW1p = (size_t)G_ * H_ * S_;   // 65536
    const size_t nW4  = (size_t)G_ * S_ * H_;   // 65536
    const size_t need = (2 * nW2 + nW1p + nW4) * sizeof(h16);

    const dim3 grid(2048), blk(NTH);            // (16384/TB) * G_

    if (ws_size >= need) {
        h16* W2p = (h16*)d_ws;
        h16* W3p = W2p + nW2;
        h16* W1p = W3p + nW2;
        h16* W4p = W1p + nW1p;
        // W2/W3: KB = 32 k-blocks of 16, Ks = 512
        packW32<<<dim3((unsigned)((nW2 / 8 + 255) / 256)), dim3(256), 0, stream>>>(W2, W2p, 32, H_);
        packW32<<<dim3((unsigned)((nW2 / 8 + 255) / 256)), dim3(256), 0, stream>>>(W3, W3p, 32, H_);
        // W1: KB = 1, Ks = 16
        packW32<<<dim3((unsigned)((nW1p / 8 + 255) / 256)), dim3(256), 0, stream>>>(W1, W1p, 1, S_);
        // W4: 16x16x32 shape: NB_total = G (16-row blocks), KB = 16, Ks = 512
        packW16<<<dim3((unsigned)((nW4 / 8 + 255) / 256)), dim3(256), 0, stream>>>(W4, W4p, G_, 16, H_);
        (void)hipFuncSetAttribute(reinterpret_cast<const void*>(mlp_fused<true>),
                                  hipFuncAttributeMaxDynamicSharedMemorySize, (int)SMEM_BYTES);
        mlp_fused<true><<<grid, blk, SMEM_BYTES, stream>>>(
            x, W1, b1, be1, W2, b2, be2, W3, b3, be3, W4, b4,
            W1p, W2p, W3p, W4p, out);
    } else {
        (void)hipFuncSetAttribute(reinterpret_cast<const void*>(mlp_fused<false>),
                                  hipFuncAttributeMaxDynamicSharedMemorySize, (int)SMEM_BYTES);
        mlp_fused<false><<<grid, blk, SMEM_BYTES, stream>>>(
            x, W1, b1, be1, W2, b2, be2, W3, b3, be3, W4, b4,
            nullptr, nullptr, nullptr, nullptr, out);
    }
}

// Round 8
// 197.233 us; speedup vs baseline: 1.2062x; 1.2062x over previous
//
#include <hip/hip_runtime.h>
#include <stdint.h>

#define G_ 8
#define S_ 16
#define H_ 512
#define TB 64
#define NTH 512

typedef _Float16 h16;
typedef _Float16 h16x8 __attribute__((ext_vector_type(8)));
typedef float f32x4 __attribute__((ext_vector_type(4)));
typedef float f32x16 __attribute__((ext_vector_type(16)));

#define XB_STRIDE 24                      // h16 units per xb row (48 B)
#define HB_BYTES (TB * 1024)              // 64 rows x 512 h16 = 64 KB
#define SMEM_BYTES (HB_BYTES + TB * XB_STRIDE * 2)   // ~67 KB -> 2 blocks/CU

__device__ __forceinline__ float swishf(float v, float sp) {
    const float e = __expf(-v * sp);
    return v * __builtin_amdgcn_rcpf(1.0f + e) * (1.0f / 1.1f);
}

// pack two f32 -> one u32 of 2x fp16 (RTZ)
__device__ __forceinline__ uint32_t pk16(float a, float b) {
    return __builtin_bit_cast(uint32_t, __builtin_amdgcn_cvt_pkrtz(a, b));
}

// swizzled byte offset into hbuf: row stride 1024B, XOR bits 4-8 with row&31.
// 32 rows at the same byte_in_row -> 32 DISTINCT 16B slots -> conflict-free
// ds_read_b128 / ds_write_b64 (old row&7 version was a 4-way conflict).
__device__ __forceinline__ uint32_t hswz(int row, uint32_t byte_in_row) {
    return (uint32_t)row * 1024u + (byte_in_row ^ (((uint32_t)(row & 31)) << 4));
}

// ---- A-operand (weight) fragment loaders ----
// 32x32x16 frag, ks-major packed layout [ks][nb=0..15][64][8]:
// wave os's 2 frags per ks sit at ONE base + {0, 1024} bytes; +16384B per ks.
// lane ln: m-row = nb*32 + (ln&31), k = ks*16 + (ln>>5)*8 + j.
template<bool USEWS>
__device__ __forceinline__ h16x8 loadA32ks(const h16* __restrict__ wpk,
                                           const float* __restrict__ wf,
                                           int ks, int nb, int ln, int Ksrc) {
    if constexpr (USEWS) {
        return *(const h16x8*)(wpk + (((size_t)ks * 16 + nb) * 64 + ln) * 8);
    } else {
        const int row = nb * 32 + (ln & 31);
        const int k = ks * 16 + (ln >> 5) * 8;
        const float* p = wf + (size_t)row * Ksrc + k;
        h16x8 r;
        #pragma unroll
        for (int j = 0; j < 8; ++j) r[j] = (h16)p[j];
        return r;
    }
}

// 16x16x32 frag (W4): lane ln: m-row = ln&15, k = ks32*32 + (ln>>4)*8 + j
template<bool USEWS>
__device__ __forceinline__ h16x8 loadA16(const h16* __restrict__ wpk,
                                         const float* __restrict__ wf,
                                         int ks32, int ln, int Ksrc) {
    if constexpr (USEWS) {
        return *(const h16x8*)(wpk + ((size_t)ks32 * 64 + ln) * 8);
    } else {
        const int row = ln & 15;
        const int k = ks32 * 32 + (ln >> 4) * 8;
        const float* p = wf + (size_t)row * Ksrc + k;
        h16x8 r;
        #pragma unroll
        for (int j = 0; j < 8; ++j) r[j] = (h16)p[j];
        return r;
    }
}

// D (32x32): col = lane&31 = batch-row b; o-row = (reg&3)+8*(reg>>2)+4*(lane>>5).
// 4 consecutive o per reg-quad -> cvt_pkrtz x2 -> one ds_write_b64.
__device__ __forceinline__ void swish_store32(const f32x16 (&acc)[2][2], char* hb,
                                              const float* __restrict__ bias, float sp,
                                              int wc0, int ln) {
    const int l31 = ln & 31, lh = ln >> 5;
    #pragma unroll
    for (int ot = 0; ot < 2; ++ot) {
        #pragma unroll
        for (int rq = 0; rq < 4; ++rq) {
            const int col0 = wc0 + ot * 32 + rq * 8 + lh * 4;
            const f32x4 bv = *(const f32x4*)(bias + col0);
            #pragma unroll
            for (int bt = 0; bt < 2; ++bt) {
                const int b = bt * 32 + l31;
                const float v0 = swishf(acc[ot][bt][rq * 4 + 0] + bv[0], sp);
                const float v1 = swishf(acc[ot][bt][rq * 4 + 1] + bv[1], sp);
                const float v2 = swishf(acc[ot][bt][rq * 4 + 2] + bv[2], sp);
                const float v3 = swishf(acc[ot][bt][rq * 4 + 3] + bv[3], sp);
                const uint64_t u = (uint64_t)pk16(v0, v1)
                                 | ((uint64_t)pk16(v2, v3) << 32);
                *(uint64_t*)(hb + hswz(b, (uint32_t)(col0 * 2))) = u;
            }
        }
    }
}

// One H->H layer: wave tile 64 o-cols x 64 b-rows, 32x32x16 MFMA, K=512.
// A: global/L2, ks-major layout, explicit DEPTH-1 prefetch (16 VGPR only —
// round 5's depth-2 + B-dbuf and round 7's 4-frag hoist both spilled).
// B: in-iter LDS reads (conflict-free swizzle; lgkmcnt fine-grained).
template<bool USEWS>
__device__ __forceinline__ void layerH32(f32x16 (&acc)[2][2],
                                         const h16* __restrict__ wpk, const float* __restrict__ wf,
                                         const char* __restrict__ hb, int os, int ln) {
    const int l31 = ln & 31, lh = ln >> 5;
    const int nb0 = os * 2;
    #pragma unroll
    for (int ot = 0; ot < 2; ++ot)
        #pragma unroll
        for (int bt = 0; bt < 2; ++bt) acc[ot][bt] = (f32x16)(0.f);

    h16x8 aC0 = loadA32ks<USEWS>(wpk, wf, 0, nb0 + 0, ln, H_);
    h16x8 aC1 = loadA32ks<USEWS>(wpk, wf, 0, nb0 + 1, ln, H_);

    #pragma unroll 2
    for (int ks = 0; ks < 32; ++ks) {
        const int ksn = (ks + 1 < 32) ? ks + 1 : 0;    // clamped dummy at tail
        h16x8 aN0 = loadA32ks<USEWS>(wpk, wf, ksn, nb0 + 0, ln, H_);
        h16x8 aN1 = loadA32ks<USEWS>(wpk, wf, ksn, nb0 + 1, ln, H_);
        const h16x8 b0 = *(const h16x8*)(hb + hswz(l31,      (uint32_t)(ks * 32 + lh * 16)));
        const h16x8 b1 = *(const h16x8*)(hb + hswz(32 + l31, (uint32_t)(ks * 32 + lh * 16)));
        __builtin_amdgcn_s_setprio(1);
        acc[0][0] = __builtin_amdgcn_mfma_f32_32x32x16_f16(aC0, b0, acc[0][0], 0, 0, 0);
        acc[0][1] = __builtin_amdgcn_mfma_f32_32x32x16_f16(aC0, b1, acc[0][1], 0, 0, 0);
        acc[1][0] = __builtin_amdgcn_mfma_f32_32x32x16_f16(aC1, b0, acc[1][0], 0, 0, 0);
        acc[1][1] = __builtin_amdgcn_mfma_f32_32x32x16_f16(aC1, b1, acc[1][1], 0, 0, 0);
        __builtin_amdgcn_s_setprio(0);
        aC0 = aN0; aC1 = aN1;
    }
}

template<bool USEWS>
__global__ __launch_bounds__(NTH, 4) void mlp_fused(
    const float* __restrict__ x,
    const float* __restrict__ W1f, const float* __restrict__ b1, const float* __restrict__ be1,
    const float* __restrict__ W2f, const float* __restrict__ b2, const float* __restrict__ be2,
    const float* __restrict__ W3f, const float* __restrict__ b3, const float* __restrict__ be3,
    const float* __restrict__ W4f, const float* __restrict__ b4,
    const h16* __restrict__ W1p, const h16* __restrict__ W2p,
    const h16* __restrict__ W3p, const h16* __restrict__ W4p,
    float* __restrict__ out) {
    extern __shared__ char smem[];
    h16* __restrict__ xb = (h16*)(smem + HB_BYTES);

    const int bid = blockIdx.x;
    const int g = bid & 7;                 // group == XCD; co-resident blocks share weights in L2
    const int rowbase = (bid >> 3) * TB;
    const int tid = threadIdx.x;
    const int wv = tid >> 6;
    const int ln = tid & 63;
    const int l31 = ln & 31;
    const int lh = ln >> 5;
    const int wc0 = wv * 64;               // 8 waves x 64-col slices over [64 rows][512 cols]

    const float sp1 = log1pf(__expf(be1[g]));
    const float sp2 = log1pf(__expf(be2[g]));
    const float sp3 = log1pf(__expf(be3[g]));

    const h16* w1p = W1p + (size_t)g * H_ * S_;
    const h16* w2p = W2p + (size_t)g * H_ * H_;
    const h16* w3p = W3p + (size_t)g * H_ * H_;
    const h16* w4p = W4p + (size_t)g * S_ * H_;
    const float* w1f = W1f + (size_t)g * H_ * S_;
    const float* w2f = W2f + (size_t)g * H_ * H_;
    const float* w3f = W3f + (size_t)g * H_ * H_;
    const float* w4f = W4f + (size_t)g * S_ * H_;

    // stage x tile -> fp16 (K=16 exact for 32x32x16)
    {
        const int idx = tid * 2;                         // 64*16 = 1024 h16, 2 per thread
        const int r = idx >> 4, s = idx & 15;
        const float2 v = *(const float2*)(x + (size_t)(rowbase + r) * (G_ * S_) + g * S_ + s);
        *(uint32_t*)((char*)xb + (r * XB_STRIDE + s) * 2) = pk16(v.x, v.y);
    }
    __syncthreads();

    f32x16 acc[2][2];

    // ---- layer 1: A=W1[512,16] frags, B=x frags, single K-step ----
    {
        #pragma unroll
        for (int ot = 0; ot < 2; ++ot)
            #pragma unroll
            for (int bt = 0; bt < 2; ++bt) acc[ot][bt] = (f32x16)(0.f);
        h16x8 aW[2], bX[2];
        #pragma unroll
        for (int ot = 0; ot < 2; ++ot)
            aW[ot] = loadA32ks<USEWS>(w1p, w1f, 0, wv * 2 + ot, ln, S_);
        #pragma unroll
        for (int bt = 0; bt < 2; ++bt)
            bX[bt] = *(const h16x8*)(xb + (bt * 32 + l31) * XB_STRIDE + lh * 8);
        #pragma unroll
        for (int ot = 0; ot < 2; ++ot)
            #pragma unroll
            for (int bt = 0; bt < 2; ++bt)
                acc[ot][bt] = __builtin_amdgcn_mfma_f32_32x32x16_f16(aW[ot], bX[bt],
                                                                     acc[ot][bt], 0, 0, 0);
    }
    swish_store32(acc, smem, b1 + g * H_, sp1, wc0, ln);
    __syncthreads();

    // ---- layer 2 ----
    layerH32<USEWS>(acc, w2p, w2f, smem, wv, ln);
    __syncthreads();                       // all hbuf reads done
    swish_store32(acc, smem, b2 + g * H_, sp2, wc0, ln);
    __syncthreads();

    // ---- layer 3 ----
    layerH32<USEWS>(acc, w3p, w3f, smem, wv, ln);
    __syncthreads();
    swish_store32(acc, smem, b3 + g * H_, sp3, wc0, ln);
    __syncthreads();

    // ---- layer 4: A=W4[16,512] frags (16x16x32), B=act; D: col=b, rows=4 consec s ----
    if (wv < 4) {
        f32x4 a4 = {0.f, 0.f, 0.f, 0.f};
        const int l15 = ln & 15, lq = ln >> 4;
        #pragma unroll 4
        for (int ks = 0; ks < 16; ++ks) {
            const h16x8 a = loadA16<USEWS>(w4p, w4f, ks, ln, H_);
            const h16x8 b = *(const h16x8*)(smem + hswz(wv * 16 + l15,
                                                        (uint32_t)(ks * 64 + lq * 16)));
            a4 = __builtin_amdgcn_mfma_f32_16x16x32_f16(a, b, a4, 0, 0, 0);
        }
        const int brow = wv * 16 + l15;    // batch row
        const int s0 = lq * 4;             // 4 consecutive state channels
        const f32x4 bv = *(const f32x4*)(b4 + g * S_ + s0);
        f32x4 o4;
        #pragma unroll
        for (int r = 0; r < 4; ++r) o4[r] = a4[r] + bv[r];
        *(f32x4*)(out + (size_t)(rowbase + brow) * (G_ * S_) + g * S_ + s0) = o4;
    }
}

// ---- weight repack (32x32x16, ks-major): fp32 [G*N][Ks] -> per-group [ks][nb][64][8] ----
__global__ void packW32(const float* __restrict__ s, h16* __restrict__ d,
                        int KB, int Ks) {
    const int t = blockIdx.x * 256 + threadIdx.x;
    const int total = G_ * KB * 16 * 64;
    if (t >= total) return;
    const int ln = t & 63;
    const int blk = t >> 6;                // ((g*KB + ks)*16 + nb)
    const int nb = blk & 15;
    const int rest = blk >> 4;
    const int ks = rest % KB;
    const int g = rest / KB;
    const int row = g * H_ + nb * 32 + (ln & 31);
    const int k = ks * 16 + (ln >> 5) * 8;
    const float* p = s + (size_t)row * Ks + k;
    h16x8 o;
    #pragma unroll
    for (int j = 0; j < 8; ++j) o[j] = (h16)p[j];
    *(h16x8*)(d + (size_t)t * 8) = o;
}

// ---- weight repack (16x16x32, W4): fp32 [G*16][512] -> per-group [ks][64][8] ----
__global__ void packW16(const float* __restrict__ s, h16* __restrict__ d,
                        int NB_total, int KB, int Ks) {
    const int t = blockIdx.x * 256 + threadIdx.x;
    const int total = NB_total * KB * 64;
    if (t >= total) return;
    const int ln = t & 63;
    const int blk = t >> 6;
    const int kb = blk % KB;
    const int nbg = blk / KB;
    const int row = nbg * 16 + (ln & 15);
    const int k = kb * 32 + (ln >> 4) * 8;
    const float* p = s + (size_t)row * Ks + k;
    h16x8 o;
    #pragma unroll
    for (int j = 0; j < 8; ++j) o[j] = (h16)p[j];
    *(h16x8*)(d + (size_t)t * 8) = o;
}

extern "C" void kernel_launch(void* const* d_in, const int* in_sizes, int n_in,
                              void* d_out, int out_size, void* d_ws, size_t ws_size,
                              hipStream_t stream) {
    const float* x   = (const float*)d_in[0];
    const float* W1  = (const float*)d_in[1];
    const float* b1  = (const float*)d_in[2];
    const float* be1 = (const float*)d_in[3];
    const float* W2  = (const float*)d_in[4];
    const float* b2  = (const float*)d_in[5];
    const float* be2 = (const float*)d_in[6];
    const float* W3  = (const float*)d_in[7];
    const float* b3  = (const float*)d_in[8];
    const float* be3 = (const float*)d_in[9];
    const float* W4  = (const float*)d_in[10];
    const float* b4  = (const float*)d_in[11];
    float* out = (float*)d_out;

    const size_t nW2  = (size_t)G_ * H_ * H_;   // 2097152
    const size_t nW1p = (size_t)G_ * H_ * S_;   // 65536
    const size_t nW4  = (size_t)G_ * S_ * H_;   // 65536
    const size_t need = (2 * nW2 + nW1p + nW4) * sizeof(h16);

    const dim3 grid(2048), blk(NTH);            // (16384/TB) * G_

    if (ws_size >= need) {
        h16* W2p = (h16*)d_ws;
        h16* W3p = W2p + nW2;
        h16* W1p = W3p + nW2;
        h16* W4p = W1p + nW1p;
        // W2/W3: KB = 32 k-blocks of 16, Ks = 512
        packW32<<<dim3((unsigned)((nW2 / 8 + 255) / 256)), dim3(256), 0, stream>>>(W2, W2p, 32, H_);
        packW32<<<dim3((unsigned)((nW2 / 8 + 255) / 256)), dim3(256), 0, stream>>>(W3, W3p, 32, H_);
        // W1: KB = 1, Ks = 16
        packW32<<<dim3((unsigned)((nW1p / 8 + 255) / 256)), dim3(256), 0, stream>>>(W1, W1p, 1, S_);
        // W4: 16x16x32 shape: NB_total = G (16-row blocks), KB = 16, Ks = 512
        packW16<<<dim3((unsigned)((nW4 / 8 + 255) / 256)), dim3(256), 0, stream>>>(W4, W4p, G_, 16, H_);
        (void)hipFuncSetAttribute(reinterpret_cast<const void*>(mlp_fused<true>),
                                  hipFuncAttributeMaxDynamicSharedMemorySize, (int)SMEM_BYTES);
        mlp_fused<true><<<grid, blk, SMEM_BYTES, stream>>>(
            x, W1, b1, be1, W2, b2, be2, W3, b3, be3, W4, b4,
            W1p, W2p, W3p, W4p, out);
    } else {
        (void)hipFuncSetAttribute(reinterpret_cast<const void*>(mlp_fused<false>),
                                  hipFuncAttributeMaxDynamicSharedMemorySize, (int)SMEM_BYTES);
        mlp_fused<false><<<grid, blk, SMEM_BYTES, stream>>>(
            x, W1, b1, be1, W2, b2, be2, W3, b3, be3, W4, b4,
            nullptr, nullptr, nullptr, nullptr, out);
    }
}